// Round 7
// baseline (1332.915 us; speedup 1.0000x reference)
//
#include <hip/hip_runtime.h>
#include <hip/hip_bf16.h>
#include <math.h>

// ---------------- constants ----------------
#define BB 32
#define LL 12
#define NN 2048
#define DD 64
#define TOPK 8
#define NKER 16
#define OUTL 12
#define HS 768
#define HT 832
#define HTP2 1024   // HT padded to 256-multiple for 256-wide N tiles
#define HCB 99
#define BN (BB*NN)   // 65536 tokens

typedef __attribute__((ext_vector_type(8))) short bf16x8;
typedef __attribute__((ext_vector_type(4))) float f32x4;

// global -> LDS direct copy, 16B per lane (dest = wave-uniform base + lane*16)
#define GLOAD16(gp, lp) __builtin_amdgcn_global_load_lds( \
    (const __attribute__((address_space(1))) unsigned int*)(uintptr_t)(gp), \
    (__attribute__((address_space(3))) unsigned int*)(unsigned int)(uintptr_t)(lp), \
    16, 0, 0)

// ---------------- f32 -> bf16 convert with zero row padding ----------------
__global__ __launch_bounds__(256)
void f2b_pad_kernel(const float* __restrict__ x, __hip_bfloat16* __restrict__ y,
                    int rows, int cols, int prows) {
    int i = blockIdx.x * 256 + threadIdx.x;
    if (i >= prows * cols) return;
    int r = i / cols;
    y[i] = __float2bfloat16((r < rows) ? x[i] : 0.f);
}

// ---------------- EmbeddingTrainer ----------------
__global__ __launch_bounds__(64)
void et_z_kernel(const float* __restrict__ node_emb, const float* __restrict__ w1,
                 const float* __restrict__ b1, float* __restrict__ z) {
    int hh = blockIdx.x;     // 0..98
    int d  = threadIdx.x;    // 0..63
    float acc = 0.f;
    for (int nn = 0; nn < NN; ++nn)
        acc += node_emb[nn*DD + d] * w1[(size_t)hh*NN + nn];
    acc += b1[hh];
    z[d*HCB + hh] = fmaxf(acc, 0.f);
}

__global__ __launch_bounds__(64)
void et_proj_kernel(const float* __restrict__ z, const float* __restrict__ w2,
                    const float* __restrict__ b2, float* __restrict__ proj) {
    int nn = blockIdx.x;     // 0..2047
    int d  = threadIdx.x;
    float acc = 0.f;
    for (int hh = 0; hh < HCB; ++hh)
        acc += z[d*HCB + hh] * w2[nn*HCB + hh];
    proj[nn*DD + d] = acc + b2[nn];
}

// ---------------- per-token prep ----------------
__global__ __launch_bounds__(64)
void prep_kernel(const float* __restrict__ hist, const float* __restrict__ proj,
                 const float* __restrict__ tod_emb, const float* __restrict__ dow_emb,
                 const float* __restrict__ ts_w, const float* __restrict__ feat_emb,
                 const float* __restrict__ kern, __hip_bfloat16* __restrict__ h,
                 int* __restrict__ cidx, unsigned int* __restrict__ mask) {
    const int tok = blockIdx.x;
    const int b = tok >> 11, n = tok & (NN-1);
    const int lane = threadIdx.x;
    __shared__ float xs[LL];
    __shared__ float conn_s[NKER];
    __shared__ int   idx_s[TOPK];
    __shared__ float w_s[TOPK];

    if (lane < LL)
        xs[lane] = hist[((size_t)(b*LL + lane) * NN + n) * 3];
    __syncthreads();

    if (lane < NKER) {
        float xn = 0.f;
        #pragma unroll
        for (int l = 0; l < LL; ++l) xn += xs[l]*xs[l];
        xn = sqrtf(xn) + 1e-8f;
        float kn = 0.f;
        #pragma unroll
        for (int l = 0; l < LL; ++l) { float kv = kern[lane*LL + l]; kn += kv*kv; }
        kn = sqrtf(kn) + 1e-8f;
        float dot = 0.f;
        #pragma unroll
        for (int l = 0; l < LL; ++l) dot += (xs[l]/xn) * (kern[lane*LL + l]/kn);
        conn_s[lane] = dot;
    }
    __syncthreads();

    if (lane == 0) {
        float c[NKER];
        #pragma unroll
        for (int k = 0; k < NKER; ++k) c[k] = conn_s[k];
        unsigned int mk = 0;
        for (int j = 0; j < TOPK; ++j) {
            float best = -1e30f; int bi = 0;
            #pragma unroll
            for (int k = 0; k < NKER; ++k)
                if (c[k] > best) { best = c[k]; bi = k; }   // strict >: lowest index on ties
            idx_s[j] = bi;
            w_s[j] = 1.f / (1.f + expf(-best));
            c[bi] = -1e30f;
            mk |= (1u << bi);
            cidx[(size_t)tok*TOPK + j] = bi;
        }
        mask[tok] = mk;
    }
    __syncthreads();

    const int d = lane;
    float ts = 0.f;
    #pragma unroll
    for (int l = 0; l < LL; ++l) ts += xs[l] * ts_w[d*LL + l];
    size_t base = (size_t)tok * HT;
    h[base + d] = __float2bfloat16(ts);
    h[base + DD + d] = __float2bfloat16(proj[n*DD + d]);
    size_t last = ((size_t)(b*LL + (LL-1)) * NN + n) * 3;
    int ti = (int)(hist[last + 1] * 288.f);
    int wi = (int)(hist[last + 2] * 7.f);
    h[base + 2*DD + d] = __float2bfloat16(tod_emb[ti*DD + d]);
    h[base + 3*DD + d] = __float2bfloat16(dow_emb[wi*DD + d]);
    #pragma unroll
    for (int j = 0; j < TOPK; ++j)
        h[base + 4*DD + j*DD + d] = __float2bfloat16(w_s[j] * feat_emb[idx_s[j]*DD + d]);
}

// ================= 256x256 bf16 MFMA GEMM, BK=64, dbuf + counted vmcnt ==========
// C[m][n] (+)= sum_k A[m][k]*W[n][k] + bias[n]
// 512 threads (8 waves, 2M x 4N; per-wave 128x64 output = 8x4 16x16 frags).
// LDS 128 KB: As[2][256*64], Bs[2][256*64] bf16, XOR-swizzled (slot' = slot ^ (row&7)).
// Schedule per K-tile t:  vmcnt(8) [stage(t) done; stage(t+1) in flight]
//   -> s_barrier -> compute(t) -> s_barrier -> issue stage(t+2) into buf[t&1].
// stage(t) latency is covered by the entire compute(t-1) (~2500 cy of MFMA).
// stage(t+2) can only write buf[t&1] after all waves finished reading tile t.
// W must have >= n0+256 valid (zero-padded) rows; epilogue guards col < NCOLS.

__device__ __forceinline__
void g256_stage(const unsigned short* ag, const unsigned short* bg,
                long long lda, long long ldb, int k0,
                unsigned short* As, unsigned short* Bs, int tid) {
    #pragma unroll
    for (int qq = 0; qq < 4; ++qq) {
        GLOAD16(ag + k0 + (long long)(qq*64)*lda, &As[(qq*512 + tid)*8]);
        GLOAD16(bg + k0 + (long long)(qq*64)*ldb, &Bs[(qq*512 + tid)*8]);
    }
}

__device__ __forceinline__
void g256_compute(const unsigned short* As, const unsigned short* Bs,
                  int wr, int wc, int l15, int l4, f32x4 acc[8][4]) {
    #pragma unroll
    for (int ks = 0; ks < 2; ++ks) {
        bf16x8 af[8], bf[4];
        #pragma unroll
        for (int i = 0; i < 8; ++i) {
            int ra = wr*128 + i*16 + l15;
            af[i] = *(const bf16x8*)&As[ra*64 + (((ks*4 + l4) ^ (ra & 7)) * 8)];
        }
        #pragma unroll
        for (int j = 0; j < 4; ++j) {
            int rb = wc*64 + j*16 + l15;
            bf[j] = *(const bf16x8*)&Bs[rb*64 + (((ks*4 + l4) ^ (rb & 7)) * 8)];
        }
        #pragma unroll
        for (int i = 0; i < 8; ++i)
            #pragma unroll
            for (int j = 0; j < 4; ++j)
                acc[i][j] = __builtin_amdgcn_mfma_f32_16x16x32_bf16(af[i], bf[j], acc[i][j], 0, 0, 0);
    }
}

template<int RELU, int ACCUM, int NCOLS>
__global__ __launch_bounds__(512, 2)
void gemm256(const unsigned short* __restrict__ A, int lda,
             const unsigned short* __restrict__ W, int ldb,
             const float* __restrict__ bias,
             __hip_bfloat16* __restrict__ C, int ldc, int K, int ntiles) {
    __shared__ __align__(16) unsigned short As[2*256*64];   // 64 KB
    __shared__ __align__(16) unsigned short Bs[2*256*64];   // 64 KB

    // bijective XCD swizzle
    int nwg = gridDim.x, bid = blockIdx.x;
    int q = nwg >> 3, r = nwg & 7;
    int xcd = bid & 7, idx = bid >> 3;
    int swz = ((xcd < r) ? xcd*(q+1) : r*(q+1) + (xcd-r)*q) + idx;
    const long long m0 = (long long)(swz / ntiles) * 256;
    const int n0 = (swz % ntiles) * 256;

    const int tid = threadIdx.x;
    const int wave = tid >> 6, lane = tid & 63;
    const int wr = wave >> 2, wc = wave & 3;        // 2M x 4N wave grid
    const int l15 = lane & 15, l4 = lane >> 4;

    // staging: round qq covers rows qq*64 + (tid>>3), slot tid&7; global col chunk
    // = (tid&7) ^ ((tid>>3)&7)  [inverse of read swizzle; row&7 == (tid>>3)&7]
    const int srow = tid >> 3;                      // 0..63
    const int gc = ((tid & 7) ^ ((tid >> 3) & 7)) * 8;
    const unsigned short* ag = A + (m0 + srow) * (long long)lda + gc;
    const unsigned short* bg = W + (long long)(n0 + srow) * ldb + gc;

    f32x4 acc[8][4] = {};
    const int NT = K >> 6;                          // 13 (MLP)

    g256_stage(ag, bg, lda, ldb, 0, As, Bs, tid);
    if (NT > 1) g256_stage(ag, bg, lda, ldb, 64, As + 256*64, Bs + 256*64, tid);

    for (int t = 0; t < NT; ++t) {
        if (t + 1 < NT) { asm volatile("s_waitcnt vmcnt(8)" ::: "memory"); }
        else            { asm volatile("s_waitcnt vmcnt(0)" ::: "memory"); }
        __builtin_amdgcn_s_barrier();               // tile t fully staged for all waves
        __builtin_amdgcn_sched_barrier(0);
        const int buf = t & 1;
        g256_compute(As + buf*256*64, Bs + buf*256*64, wr, wc, l15, l4, acc);
        __builtin_amdgcn_sched_barrier(0);
        __builtin_amdgcn_s_barrier();               // all waves done reading buf
        __builtin_amdgcn_sched_barrier(0);
        if (t + 2 < NT)
            g256_stage(ag, bg, lda, ldb, (t+2) << 6, As + buf*256*64, Bs + buf*256*64, tid);
    }

    #pragma unroll
    for (int i = 0; i < 8; ++i) {
        #pragma unroll
        for (int j = 0; j < 4; ++j) {
            int col = n0 + wc*64 + j*16 + l15;
            if (col < NCOLS) {
                float bv = bias[col];
                #pragma unroll
                for (int rg = 0; rg < 4; ++rg) {
                    long long row = m0 + wr*128 + i*16 + l4*4 + rg;
                    float v = acc[i][j][rg] + bv;
                    if (RELU) v = fmaxf(v, 0.f);
                    if (ACCUM) v += __bfloat162float(C[row*ldc + col]);
                    C[row*ldc + col] = __float2bfloat16(v);
                }
            }
        }
    }
}

// ---------------- 128x128 GEMM (round-4 structure) for the spatial projection ----------------
template<int RELU, int NCOLS>
__global__ __launch_bounds__(256)
void gemm128(const unsigned short* __restrict__ A, int lda,
             const unsigned short* __restrict__ W, int ldb,
             const float* __restrict__ bias,
             float* __restrict__ C, int ldc, int K, int ntiles) {
    __shared__ __align__(16) unsigned short As[128*64];
    __shared__ __align__(16) unsigned short Bs[128*64];

    int nwg = gridDim.x, bid = blockIdx.x;
    int q = nwg >> 3, r = nwg & 7;
    int xcd = bid & 7, idx = bid >> 3;
    int swz = ((xcd < r) ? xcd*(q+1) : r*(q+1) + (xcd-r)*q) + idx;
    const long long m0 = (long long)(swz / ntiles) * 128;
    const int n0 = (swz % ntiles) * 128;

    const int tid = threadIdx.x;
    const int wave = tid >> 6, lane = tid & 63;
    const int wr = wave >> 1, wc = wave & 1;
    const int l15 = lane & 15, l4 = lane >> 4;

    const int srow = tid >> 3;                       // 0..31
    const int gc = ((tid & 7) ^ ((tid >> 3) & 7)) * 8;
    const unsigned short* ag = A + (m0 + srow) * (long long)lda + gc;
    const unsigned short* bg = W + (long long)(n0 + srow) * ldb + gc;

    f32x4 acc[4][4] = {};

    for (int k0 = 0; k0 < K; k0 += 64) {
        #pragma unroll
        for (int qq = 0; qq < 4; ++qq) {
            GLOAD16(ag + k0 + (long long)(qq*32)*lda, &As[(qq*256 + tid)*8]);
            GLOAD16(bg + k0 + (long long)(qq*32)*ldb, &Bs[(qq*256 + tid)*8]);
        }
        __syncthreads();
        #pragma unroll
        for (int kh = 0; kh < 2; ++kh) {
            bf16x8 af[4], bf[4];
            #pragma unroll
            for (int i = 0; i < 4; ++i) {
                int ra = wr*64 + i*16 + l15;
                af[i] = *(const bf16x8*)&As[ra*64 + (((kh*4 + l4) ^ (ra & 7)) * 8)];
            }
            #pragma unroll
            for (int j = 0; j < 4; ++j) {
                int rb = wc*64 + j*16 + l15;
                bf[j] = *(const bf16x8*)&Bs[rb*64 + (((kh*4 + l4) ^ (rb & 7)) * 8)];
            }
            #pragma unroll
            for (int i = 0; i < 4; ++i)
                #pragma unroll
                for (int j = 0; j < 4; ++j)
                    acc[i][j] = __builtin_amdgcn_mfma_f32_16x16x32_bf16(af[i], bf[j], acc[i][j], 0, 0, 0);
        }
        __syncthreads();
    }

    #pragma unroll
    for (int i = 0; i < 4; ++i) {
        #pragma unroll
        for (int j = 0; j < 4; ++j) {
            int col = n0 + wc*64 + j*16 + l15;
            if (col < NCOLS) {
                float bv = bias[col];
                #pragma unroll
                for (int rg = 0; rg < 4; ++rg) {
                    long long row = m0 + wr*64 + i*16 + l4*4 + rg;
                    float v = acc[i][j][rg] + bv;
                    if (RELU) v = fmaxf(v, 0.f);
                    C[row*ldc + col] = v;
                }
            }
        }
    }
}

// ---------------- hyperedge aggregation ----------------
__global__ __launch_bounds__(256)
void edge_kernel(const float* __restrict__ h0, const unsigned int* __restrict__ mask,
                 const float* __restrict__ feat_emb, float* __restrict__ edge) {
    int b = blockIdx.x >> 4, k = blockIdx.x & 15;
    int g = threadIdx.x >> 6, d = threadIdx.x & 63;
    __shared__ float accs[4][64];
    __shared__ int cnts[4];
    float acc = 0.f; int cnt = 0;
    size_t tb = (size_t)b * NN;
    #pragma unroll 4
    for (int nn = g; nn < NN; nn += 4) {
        unsigned int bit = (mask[tb + nn] >> k) & 1u;
        acc += (float)bit * h0[(tb + nn)*DD + d];
        cnt += (int)bit;
    }
    accs[g][d] = acc;
    if (d == 0) cnts[g] = cnt;
    __syncthreads();
    if (g == 0) {
        float a = accs[0][d] + accs[1][d] + accs[2][d] + accs[3][d];
        int c = cnts[0] + cnts[1] + cnts[2] + cnts[3];
        edge[((size_t)b*NKER + k)*DD + d] = a / fmaxf((float)c, 1.f) + feat_emb[k*DD + d];
    }
}

// msg + sp_out: h[tok][768+d] = h0 + msg/8 + proj
__global__ __launch_bounds__(256)
void msg_kernel(const float* __restrict__ h0, const float* __restrict__ edge,
                const int* __restrict__ cidx, const float* __restrict__ proj,
                __hip_bfloat16* __restrict__ h) {
    __shared__ float eS[NKER*DD];
    int t0 = blockIdx.x * 4;
    int b = t0 >> 11;
    for (int i = threadIdx.x; i < NKER*DD; i += 256) eS[i] = edge[(size_t)b*NKER*DD + i];
    __syncthreads();
    int g = threadIdx.x >> 6, lane = threadIdx.x & 63;
    int tok = t0 + g, n = tok & (NN-1);
    float m = 0.f;
    #pragma unroll
    for (int j = 0; j < TOPK; ++j)
        m += eS[cidx[(size_t)tok*TOPK + j]*DD + lane];
    float sp = h0[(size_t)tok*DD + lane] + m*0.125f + proj[n*DD + lane];
    h[(size_t)tok*HT + HS + lane] = __float2bfloat16(sp);
}

// ---------------- temporal branch -> forecast_t into d_out ----------------
__global__ __launch_bounds__(256)
void temporal_kernel(const float* __restrict__ hist, const float* __restrict__ fut,
                     const float* __restrict__ daily, const float* __restrict__ weekly,
                     const float* __restrict__ treg_w, const float* __restrict__ treg_b,
                     float* __restrict__ outp) {
    __shared__ int s_di[LL], s_wi[LL], s_df[OUTL], s_wf[OUTL];
    __shared__ float s_tw[OUTL*LL], s_tb[OUTL];
    int tid = threadIdx.x;
    int tok = blockIdx.x * 256 + tid;
    int b = tok >> 11, n = tok & (NN-1);
    if (tid < LL) {
        size_t hb = ((size_t)(b*LL + tid) * NN) * 3;
        s_di[tid] = (int)(hist[hb + 1] * 288.f);
        s_wi[tid] = (int)(hist[hb + 2] * 7.f);
        size_t fb = ((size_t)(b*OUTL + tid) * NN) * 3;
        s_df[tid] = (int)(fut[fb + 1] * 288.f);
        s_wf[tid] = (int)(fut[fb + 2] * 7.f);
        s_tb[tid] = treg_b[tid];
    }
    if (tid < OUTL*LL) s_tw[tid] = treg_w[tid];
    __syncthreads();
    float x[LL];
    float mean = 0.f;
    #pragma unroll
    for (int l = 0; l < LL; ++l) {
        x[l] = hist[((size_t)(b*LL + l) * NN + n) * 3];
        mean += x[l];
    }
    mean *= (1.f/12.f);
    float ss = 0.f;
    #pragma unroll
    for (int l = 0; l < LL; ++l) { float dd = x[l]-mean; ss += dd*dd; }
    float sd = sqrtf(ss*(1.f/11.f) + 1e-5f);
    float xr[LL];
    #pragma unroll
    for (int l = 0; l < LL; ++l)
        xr[l] = (x[l]-mean)/sd - daily[(size_t)s_di[l]*NN + n] - weekly[(size_t)s_wi[l]*NN + n];
    #pragma unroll
    for (int o = 0; o < OUTL; ++o) {
        float f = s_tb[o];
        #pragma unroll
        for (int l = 0; l < LL; ++l) f += xr[l]*s_tw[o*LL + l];
        f += daily[(size_t)s_df[o]*NN + n] + weekly[(size_t)s_wf[o]*NN + n];
        f = f*sd + mean;
        outp[((size_t)b*OUTL + o)*NN + n] = f;
    }
}

// ---------------- forecast_sp + blend ----------------
__global__ __launch_bounds__(256)
void final_kernel(const __hip_bfloat16* __restrict__ h, const float* __restrict__ sreg_w,
                  const float* __restrict__ sreg_b, const float* __restrict__ w_sp,
                  float* __restrict__ outp) {
    int g = threadIdx.x >> 6, lane = threadIdx.x & 63;
    int tok = blockIdx.x*4 + g;
    int b = tok >> 11, n = tok & (NN-1);
    float acc[OUTL];
    #pragma unroll
    for (int o = 0; o < OUTL; ++o) acc[o] = 0.f;
    size_t base = (size_t)tok * HT;
    for (int c = lane; c < HT; c += 64) {
        float hv = __bfloat162float(h[base + c]);
        #pragma unroll
        for (int o = 0; o < OUTL; ++o) acc[o] += hv * sreg_w[o*HT + c];
    }
    #pragma unroll
    for (int o = 0; o < OUTL; ++o) {
        #pragma unroll
        for (int s = 32; s >= 1; s >>= 1)
            acc[o] += __shfl_xor(acc[o], s, 64);
    }
    float v = 0.f;
    #pragma unroll
    for (int o = 0; o < OUTL; ++o) if (lane == o) v = acc[o] + sreg_b[o];
    if (lane < OUTL) {
        size_t oi = ((size_t)b*OUTL + lane)*NN + n;
        float t = outp[oi];
        float w = w_sp[n];
        outp[oi] = w*v + (1.f-w)*t;
    }
}

// ---------------- launch ----------------
extern "C" void kernel_launch(void* const* d_in, const int* in_sizes, int n_in,
                              void* d_out, int out_size, void* d_ws, size_t ws_size,
                              hipStream_t stream) {
    const float* hist    = (const float*)d_in[0];
    const float* fut     = (const float*)d_in[1];
    const float* node_emb= (const float*)d_in[2];
    const float* et_w1   = (const float*)d_in[3];
    const float* et_b1   = (const float*)d_in[4];
    const float* et_w2   = (const float*)d_in[5];
    const float* et_b2   = (const float*)d_in[6];
    const float* tod_emb = (const float*)d_in[7];
    const float* dow_emb = (const float*)d_in[8];
    const float* ts_w    = (const float*)d_in[9];
    const float* feat    = (const float*)d_in[10];
    const float* kern    = (const float*)d_in[11];
    const float* sp_w    = (const float*)d_in[12];
    const float* sp_b    = (const float*)d_in[13];
    const float* mlp_w1  = (const float*)d_in[14];
    const float* mlp_b1  = (const float*)d_in[15];
    const float* mlp_w2  = (const float*)d_in[16];
    const float* mlp_b2  = (const float*)d_in[17];
    const float* treg_w  = (const float*)d_in[18];
    const float* treg_b  = (const float*)d_in[19];
    const float* sreg_w  = (const float*)d_in[20];
    const float* sreg_b  = (const float*)d_in[21];
    const float* daily   = (const float*)d_in[22];
    const float* weekly  = (const float*)d_in[23];
    const float* w_sp    = (const float*)d_in[24];
    float* out = (float*)d_out;

    char* ws = (char*)d_ws;
    __hip_bfloat16* h    = (__hip_bfloat16*)(ws);                 // BN*832 bf16 = 109,051,904
    float*          h0   = (float*)(ws + 109051904ULL);           // BN*64 f32   =  16,777,216
    float*          proj = (float*)(ws + 125829120ULL);           // N*64 f32    =     524,288
    float*          zet  = (float*)(ws + 126353408ULL);           // 64*99 f32 (pad 32,768)
    float*          edge = (float*)(ws + 126386176ULL);           // B*16*64 f32 =     131,072
    int*            cidx = (int*)  (ws + 126517248ULL);           // BN*8 i32    =   2,097,152
    unsigned int*   mask = (unsigned int*)(ws + 128614400ULL);    // BN u32      =     262,144
    __hip_bfloat16* spwb = (__hip_bfloat16*)(ws + 128876544ULL);  // 128*768 bf16=     196,608
    __hip_bfloat16* w1b  = (__hip_bfloat16*)(ws + 129073152ULL);  // 3*1024*832  =   5,111,808
    __hip_bfloat16* w2b  = (__hip_bfloat16*)(ws + 134184960ULL);  // 3*1024*832  =   5,111,808
    const size_t z1_off = 139296768ULL;
    __hip_bfloat16* z1   = (__hip_bfloat16*)(ws + z1_off);        // up to BN*832 bf16

    // adaptive z1 chunk (rows, multiple of 256)
    long long avail = (ws_size > z1_off) ? (long long)(ws_size - z1_off) : 0;
    long long chunk = (avail / (HT*2)) & ~255LL;
    if (chunk > BN) chunk = BN;
    if (chunk < 256) chunk = 256;

    // weight conversion with zero row padding (idempotent)
    f2b_pad_kernel<<<(128*HS + 255)/256, 256, 0, stream>>>(sp_w, spwb, 64, HS, 128);
    for (int i = 0; i < 3; ++i) {
        f2b_pad_kernel<<<(HTP2*HT + 255)/256, 256, 0, stream>>>(
            mlp_w1 + (size_t)i*HT*HT, w1b + (size_t)i*HTP2*HT, HT, HT, HTP2);
        f2b_pad_kernel<<<(HTP2*HT + 255)/256, 256, 0, stream>>>(
            mlp_w2 + (size_t)i*HT*HT, w2b + (size_t)i*HTP2*HT, HT, HT, HTP2);
    }

    et_z_kernel  <<<HCB, 64, 0, stream>>>(node_emb, et_w1, et_b1, zet);
    et_proj_kernel<<<NN, 64, 0, stream>>>(zet, et_w2, et_b2, proj);
    prep_kernel  <<<BN, 64, 0, stream>>>(hist, proj, tod_emb, dow_emb, ts_w, feat, kern,
                                         h, cidx, mask);
    // h0 = relu(enc_in @ sp_w^T + sp_b)  (K=768, NCOLS=64, C f32)
    gemm128<1,64><<<BN/128, 256, 0, stream>>>(
        (const unsigned short*)h, HT, (const unsigned short*)spwb, HS, sp_b, h0, DD, HS, 1);
    edge_kernel  <<<BB*NKER, 256, 0, stream>>>(h0, mask, feat, edge);
    msg_kernel   <<<BN/4, 256, 0, stream>>>(h0, edge, cidx, proj, h);
    // residual MLP stack, 256x256 tiles, chunked over M by available workspace
    for (int i = 0; i < 3; ++i) {
        for (long long ms = 0; ms < BN; ms += chunk) {
            long long mm = (BN - ms < chunk) ? (BN - ms) : chunk;
            int grid = (int)(mm/256) * (HTP2/256);
            gemm256<1,0,HT><<<grid, 512, 0, stream>>>(
                (const unsigned short*)(h + ms*HT), HT,
                (const unsigned short*)(w1b + (size_t)i*HTP2*HT), HT,
                mlp_b1 + i*HT, z1, HT, HT, HTP2/256);
            gemm256<0,1,HT><<<grid, 512, 0, stream>>>(
                (const unsigned short*)z1, HT,
                (const unsigned short*)(w2b + (size_t)i*HTP2*HT), HT,
                mlp_b2 + i*HT, h + ms*HT, HT, HT, HTP2/256);
        }
    }
    temporal_kernel<<<BN/256, 256, 0, stream>>>(hist, fut, daily, weekly, treg_w, treg_b, out);
    final_kernel <<<BN/4, 256, 0, stream>>>(h, sreg_w, sreg_b, w_sp, out);
}

// Round 8
// 1295.662 us; speedup vs baseline: 1.0288x; 1.0288x over previous
//
#include <hip/hip_runtime.h>
#include <hip/hip_bf16.h>
#include <math.h>

// ---------------- constants ----------------
#define BB 32
#define LL 12
#define NN 2048
#define DD 64
#define TOPK 8
#define NKER 16
#define OUTL 12
#define HS 768
#define HT 832
#define HTP 896     // HT padded to 128-multiple for 128-wide N tiles
#define HCB 99
#define BN (BB*NN)   // 65536 tokens

typedef __attribute__((ext_vector_type(8))) short bf16x8;
typedef __attribute__((ext_vector_type(4))) float f32x4;

// global -> LDS direct copy, 16B per lane (dest = wave-uniform base + lane*16)
#define GLOAD16(gp, lp) __builtin_amdgcn_global_load_lds( \
    (const __attribute__((address_space(1))) unsigned int*)(uintptr_t)(gp), \
    (__attribute__((address_space(3))) unsigned int*)(unsigned int)(uintptr_t)(lp), \
    16, 0, 0)

// ---------------- f32 -> bf16 convert with zero row padding ----------------
__global__ __launch_bounds__(256)
void f2b_pad_kernel(const float* __restrict__ x, __hip_bfloat16* __restrict__ y,
                    int rows, int cols, int prows) {
    int i = blockIdx.x * 256 + threadIdx.x;
    if (i >= prows * cols) return;
    int r = i / cols;
    y[i] = __float2bfloat16((r < rows) ? x[i] : 0.f);
}

// ---------------- EmbeddingTrainer ----------------
__global__ __launch_bounds__(64)
void et_z_kernel(const float* __restrict__ node_emb, const float* __restrict__ w1,
                 const float* __restrict__ b1, float* __restrict__ z) {
    int hh = blockIdx.x;     // 0..98
    int d  = threadIdx.x;    // 0..63
    float acc = 0.f;
    for (int nn = 0; nn < NN; ++nn)
        acc += node_emb[nn*DD + d] * w1[(size_t)hh*NN + nn];
    acc += b1[hh];
    z[d*HCB + hh] = fmaxf(acc, 0.f);
}

__global__ __launch_bounds__(64)
void et_proj_kernel(const float* __restrict__ z, const float* __restrict__ w2,
                    const float* __restrict__ b2, float* __restrict__ proj) {
    int nn = blockIdx.x;     // 0..2047
    int d  = threadIdx.x;
    float acc = 0.f;
    for (int hh = 0; hh < HCB; ++hh)
        acc += z[d*HCB + hh] * w2[nn*HCB + hh];
    proj[nn*DD + d] = acc + b2[nn];
}

// ---------------- per-token prep ----------------
__global__ __launch_bounds__(64)
void prep_kernel(const float* __restrict__ hist, const float* __restrict__ proj,
                 const float* __restrict__ tod_emb, const float* __restrict__ dow_emb,
                 const float* __restrict__ ts_w, const float* __restrict__ feat_emb,
                 const float* __restrict__ kern, __hip_bfloat16* __restrict__ h,
                 int* __restrict__ cidx, unsigned int* __restrict__ mask) {
    const int tok = blockIdx.x;
    const int b = tok >> 11, n = tok & (NN-1);
    const int lane = threadIdx.x;
    __shared__ float xs[LL];
    __shared__ float conn_s[NKER];
    __shared__ int   idx_s[TOPK];
    __shared__ float w_s[TOPK];

    if (lane < LL)
        xs[lane] = hist[((size_t)(b*LL + lane) * NN + n) * 3];
    __syncthreads();

    if (lane < NKER) {
        float xn = 0.f;
        #pragma unroll
        for (int l = 0; l < LL; ++l) xn += xs[l]*xs[l];
        xn = sqrtf(xn) + 1e-8f;
        float kn = 0.f;
        #pragma unroll
        for (int l = 0; l < LL; ++l) { float kv = kern[lane*LL + l]; kn += kv*kv; }
        kn = sqrtf(kn) + 1e-8f;
        float dot = 0.f;
        #pragma unroll
        for (int l = 0; l < LL; ++l) dot += (xs[l]/xn) * (kern[lane*LL + l]/kn);
        conn_s[lane] = dot;
    }
    __syncthreads();

    if (lane == 0) {
        float c[NKER];
        #pragma unroll
        for (int k = 0; k < NKER; ++k) c[k] = conn_s[k];
        unsigned int mk = 0;
        for (int j = 0; j < TOPK; ++j) {
            float best = -1e30f; int bi = 0;
            #pragma unroll
            for (int k = 0; k < NKER; ++k)
                if (c[k] > best) { best = c[k]; bi = k; }   // strict >: lowest index on ties
            idx_s[j] = bi;
            w_s[j] = 1.f / (1.f + expf(-best));
            c[bi] = -1e30f;
            mk |= (1u << bi);
            cidx[(size_t)tok*TOPK + j] = bi;
        }
        mask[tok] = mk;
    }
    __syncthreads();

    const int d = lane;
    float ts = 0.f;
    #pragma unroll
    for (int l = 0; l < LL; ++l) ts += xs[l] * ts_w[d*LL + l];
    size_t base = (size_t)tok * HT;
    h[base + d] = __float2bfloat16(ts);
    h[base + DD + d] = __float2bfloat16(proj[n*DD + d]);
    size_t last = ((size_t)(b*LL + (LL-1)) * NN + n) * 3;
    int ti = (int)(hist[last + 1] * 288.f);
    int wi = (int)(hist[last + 2] * 7.f);
    h[base + 2*DD + d] = __float2bfloat16(tod_emb[ti*DD + d]);
    h[base + 3*DD + d] = __float2bfloat16(dow_emb[wi*DD + d]);
    #pragma unroll
    for (int j = 0; j < TOPK; ++j)
        h[base + 4*DD + j*DD + d] = __float2bfloat16(w_s[j] * feat_emb[idx_s[j]*DD + d]);
}

// ---------------- bf16 MFMA GEMM, BK=64, stage-early dbuf, ONE barrier/tile ----------------
// C[m][n] (+)= sum_k A[m][k]*W[n][k] + bias[n]
// 128x128 tile, BK=64, 256 threads (2x2 waves, 4x4 frags), 32 MFMA/wave per tile.
// T3 "minimum 2-phase": issue STAGE(t+1) into buf^1 BEFORE compute(t) on buf, then a
// single __syncthreads() (its vmcnt(0) drains a prefetch that compute already covered).
// ds_reads(buf) and gload_lds writes(buf^1) can't alias -> no asm fences needed; the
// compiler keeps its own interleave (r6's sched_barriers cost 15pts of VALUBusy).
// Hazard: stage(t+1) overwrites the buffer last read at t-1; all waves passed the
// end-of-(t-1) barrier (lgkmcnt(0) drained) before any wave issues stage(t+1).
// XOR-swizzled ds_read (slot' = slot ^ (row&7)); inverse-swizzled global source.
// W must have >= n0+128 valid rows (zero-padded); epilogue guards col < NCOLS.

__device__ __forceinline__
void compute64(const unsigned short* As, const unsigned short* Bs,
               int wr, int wc, int l15, int l4, f32x4 acc[4][4]) {
    #pragma unroll
    for (int kh = 0; kh < 2; ++kh) {
        bf16x8 af[4], bf[4];
        #pragma unroll
        for (int i = 0; i < 4; ++i) {
            int ra = wr*64 + i*16 + l15;
            af[i] = *(const bf16x8*)&As[ra*64 + (((kh*4 + l4) ^ (ra & 7)) * 8)];
        }
        #pragma unroll
        for (int j = 0; j < 4; ++j) {
            int rb = wc*64 + j*16 + l15;
            bf[j] = *(const bf16x8*)&Bs[rb*64 + (((kh*4 + l4) ^ (rb & 7)) * 8)];
        }
        #pragma unroll
        for (int i = 0; i < 4; ++i)
            #pragma unroll
            for (int j = 0; j < 4; ++j)
                acc[i][j] = __builtin_amdgcn_mfma_f32_16x16x32_bf16(af[i], bf[j], acc[i][j], 0, 0, 0);
    }
}

__device__ __forceinline__
void stage64(const unsigned short* ag, const unsigned short* bg, long long lda, long long ldb,
             int k0, unsigned short* As, unsigned short* Bs, int tid) {
    #pragma unroll
    for (int qq = 0; qq < 4; ++qq) {
        GLOAD16(ag + k0 + qq*32*lda, &As[(qq*256 + tid)*8]);
        GLOAD16(bg + k0 + qq*32*ldb, &Bs[(qq*256 + tid)*8]);
    }
}

template<int RELU, int ACCUM, int CF32, int NCOLS>
__global__ __launch_bounds__(256)
void gemm128(const unsigned short* __restrict__ A, int lda,
             const unsigned short* __restrict__ W, int ldb,
             const float* __restrict__ bias,
             void* __restrict__ Cp, int ldc, int K, int ntiles) {
    __shared__ __align__(16) unsigned short As[2][128*64];   // 2 x 16 KB
    __shared__ __align__(16) unsigned short Bs[2][128*64];   // 2 x 16 KB

    // bijective XCD swizzle
    int nwg = gridDim.x, bid = blockIdx.x;
    int q = nwg >> 3, r = nwg & 7;
    int xcd = bid & 7, idx = bid >> 3;
    int swz = ((xcd < r) ? xcd*(q+1) : r*(q+1) + (xcd-r)*q) + idx;
    const long long m0 = (long long)(swz / ntiles) * 128;
    const int n0 = (swz % ntiles) * 128;

    const int tid = threadIdx.x;
    const int wave = tid >> 6, lane = tid & 63;
    const int wr = wave >> 1, wc = wave & 1;
    const int l15 = lane & 15, l4 = lane >> 4;

    // staging coords: thread t fills LDS row qq*32 + (t>>3), slot t&7; global col
    // chunk (t&7) ^ ((t>>3)&7)  [inverse of the read swizzle; row&7 == (t>>3)&7]
    const int srow = tid >> 3;                       // 0..31
    const int gc = ((tid & 7) ^ ((tid >> 3) & 7)) * 8;
    const unsigned short* ag = A + (m0 + srow) * (long long)lda + gc;
    const unsigned short* bg = W + (long long)(n0 + srow) * ldb + gc;

    f32x4 acc[4][4] = {};
    const int nsteps = K >> 6;                       // 12 or 13

    stage64(ag, bg, lda, ldb, 0, As[0], Bs[0], tid);
    __syncthreads();                                 // publish tile 0
    int cur = 0;
    for (int t = 0; t < nsteps; ++t) {
        if (t + 1 < nsteps)
            stage64(ag, bg, lda, ldb, (t+1) << 6, As[cur^1], Bs[cur^1], tid);  // issue early
        compute64(As[cur], Bs[cur], wr, wc, l15, l4, acc);                     // hides latency
        __syncthreads();                             // drain prefetch (mostly done) + publish
        cur ^= 1;
    }

    float* Cf = (float*)Cp;
    __hip_bfloat16* Cb = (__hip_bfloat16*)Cp;
    #pragma unroll
    for (int i = 0; i < 4; ++i) {
        #pragma unroll
        for (int j = 0; j < 4; ++j) {
            int col = n0 + wc*64 + j*16 + l15;
            if (col < NCOLS) {
                float bv = bias[col];
                #pragma unroll
                for (int rg = 0; rg < 4; ++rg) {
                    long long row = m0 + wr*64 + i*16 + l4*4 + rg;
                    float v = acc[i][j][rg] + bv;
                    if (RELU) v = fmaxf(v, 0.f);
                    if (CF32) {
                        Cf[row*ldc + col] = v;
                    } else {
                        if (ACCUM) v += __bfloat162float(Cb[row*ldc + col]);
                        Cb[row*ldc + col] = __float2bfloat16(v);
                    }
                }
            }
        }
    }
}

// ---------------- hyperedge aggregation (unconditional, pipelined) ----------------
__global__ __launch_bounds__(256)
void edge_kernel(const float* __restrict__ h0, const unsigned int* __restrict__ mask,
                 const float* __restrict__ feat_emb, float* __restrict__ edge) {
    int b = blockIdx.x >> 4, k = blockIdx.x & 15;
    int g = threadIdx.x >> 6, d = threadIdx.x & 63;
    __shared__ float accs[4][64];
    __shared__ int cnts[4];
    float acc = 0.f; int cnt = 0;
    size_t tb = (size_t)b * NN;
    #pragma unroll 4
    for (int nn = g; nn < NN; nn += 4) {
        unsigned int bit = (mask[tb + nn] >> k) & 1u;
        acc += (float)bit * h0[(tb + nn)*DD + d];
        cnt += (int)bit;
    }
    accs[g][d] = acc;
    if (d == 0) cnts[g] = cnt;
    __syncthreads();
    if (g == 0) {
        float a = accs[0][d] + accs[1][d] + accs[2][d] + accs[3][d];
        int c = cnts[0] + cnts[1] + cnts[2] + cnts[3];
        edge[((size_t)b*NKER + k)*DD + d] = a / fmaxf((float)c, 1.f) + feat_emb[k*DD + d];
    }
}

// msg + sp_out: h[tok][768+d] = h0 + msg/8 + proj
__global__ __launch_bounds__(256)
void msg_kernel(const float* __restrict__ h0, const float* __restrict__ edge,
                const int* __restrict__ cidx, const float* __restrict__ proj,
                __hip_bfloat16* __restrict__ h) {
    __shared__ float eS[NKER*DD];
    int t0 = blockIdx.x * 4;
    int b = t0 >> 11;
    for (int i = threadIdx.x; i < NKER*DD; i += 256) eS[i] = edge[(size_t)b*NKER*DD + i];
    __syncthreads();
    int g = threadIdx.x >> 6, lane = threadIdx.x & 63;
    int tok = t0 + g, n = tok & (NN-1);
    float m = 0.f;
    #pragma unroll
    for (int j = 0; j < TOPK; ++j)
        m += eS[cidx[(size_t)tok*TOPK + j]*DD + lane];
    float sp = h0[(size_t)tok*DD + lane] + m*0.125f + proj[n*DD + lane];
    h[(size_t)tok*HT + HS + lane] = __float2bfloat16(sp);
}

// ---------------- temporal branch -> forecast_t into d_out ----------------
__global__ __launch_bounds__(256)
void temporal_kernel(const float* __restrict__ hist, const float* __restrict__ fut,
                     const float* __restrict__ daily, const float* __restrict__ weekly,
                     const float* __restrict__ treg_w, const float* __restrict__ treg_b,
                     float* __restrict__ outp) {
    __shared__ int s_di[LL], s_wi[LL], s_df[OUTL], s_wf[OUTL];
    __shared__ float s_tw[OUTL*LL], s_tb[OUTL];
    int tid = threadIdx.x;
    int tok = blockIdx.x * 256 + tid;
    int b = tok >> 11, n = tok & (NN-1);
    if (tid < LL) {
        size_t hb = ((size_t)(b*LL + tid) * NN) * 3;
        s_di[tid] = (int)(hist[hb + 1] * 288.f);
        s_wi[tid] = (int)(hist[hb + 2] * 7.f);
        size_t fb = ((size_t)(b*OUTL + tid) * NN) * 3;
        s_df[tid] = (int)(fut[fb + 1] * 288.f);
        s_wf[tid] = (int)(fut[fb + 2] * 7.f);
        s_tb[tid] = treg_b[tid];
    }
    if (tid < OUTL*LL) s_tw[tid] = treg_w[tid];
    __syncthreads();
    float x[LL];
    float mean = 0.f;
    #pragma unroll
    for (int l = 0; l < LL; ++l) {
        x[l] = hist[((size_t)(b*LL + l) * NN + n) * 3];
        mean += x[l];
    }
    mean *= (1.f/12.f);
    float ss = 0.f;
    #pragma unroll
    for (int l = 0; l < LL; ++l) { float dd = x[l]-mean; ss += dd*dd; }
    float sd = sqrtf(ss*(1.f/11.f) + 1e-5f);
    float xr[LL];
    #pragma unroll
    for (int l = 0; l < LL; ++l)
        xr[l] = (x[l]-mean)/sd - daily[(size_t)s_di[l]*NN + n] - weekly[(size_t)s_wi[l]*NN + n];
    #pragma unroll
    for (int o = 0; o < OUTL; ++o) {
        float f = s_tb[o];
        #pragma unroll
        for (int l = 0; l < LL; ++l) f += xr[l]*s_tw[o*LL + l];
        f += daily[(size_t)s_df[o]*NN + n] + weekly[(size_t)s_wf[o]*NN + n];
        f = f*sd + mean;
        outp[((size_t)b*OUTL + o)*NN + n] = f;
    }
}

// ---------------- forecast_sp + blend ----------------
__global__ __launch_bounds__(256)
void final_kernel(const __hip_bfloat16* __restrict__ h, const float* __restrict__ sreg_w,
                  const float* __restrict__ sreg_b, const float* __restrict__ w_sp,
                  float* __restrict__ outp) {
    int g = threadIdx.x >> 6, lane = threadIdx.x & 63;
    int tok = blockIdx.x*4 + g;
    int b = tok >> 11, n = tok & (NN-1);
    float acc[OUTL];
    #pragma unroll
    for (int o = 0; o < OUTL; ++o) acc[o] = 0.f;
    size_t base = (size_t)tok * HT;
    for (int c = lane; c < HT; c += 64) {
        float hv = __bfloat162float(h[base + c]);
        #pragma unroll
        for (int o = 0; o < OUTL; ++o) acc[o] += hv * sreg_w[o*HT + c];
    }
    #pragma unroll
    for (int o = 0; o < OUTL; ++o) {
        #pragma unroll
        for (int s = 32; s >= 1; s >>= 1)
            acc[o] += __shfl_xor(acc[o], s, 64);
    }
    float v = 0.f;
    #pragma unroll
    for (int o = 0; o < OUTL; ++o) if (lane == o) v = acc[o] + sreg_b[o];
    if (lane < OUTL) {
        size_t oi = ((size_t)b*OUTL + lane)*NN + n;
        float t = outp[oi];
        float w = w_sp[n];
        outp[oi] = w*v + (1.f-w)*t;
    }
}

// ---------------- launch ----------------
extern "C" void kernel_launch(void* const* d_in, const int* in_sizes, int n_in,
                              void* d_out, int out_size, void* d_ws, size_t ws_size,
                              hipStream_t stream) {
    const float* hist    = (const float*)d_in[0];
    const float* fut     = (const float*)d_in[1];
    const float* node_emb= (const float*)d_in[2];
    const float* et_w1   = (const float*)d_in[3];
    const float* et_b1   = (const float*)d_in[4];
    const float* et_w2   = (const float*)d_in[5];
    const float* et_b2   = (const float*)d_in[6];
    const float* tod_emb = (const float*)d_in[7];
    const float* dow_emb = (const float*)d_in[8];
    const float* ts_w    = (const float*)d_in[9];
    const float* feat    = (const float*)d_in[10];
    const float* kern    = (const float*)d_in[11];
    const float* sp_w    = (const float*)d_in[12];
    const float* sp_b    = (const float*)d_in[13];
    const float* mlp_w1  = (const float*)d_in[14];
    const float* mlp_b1  = (const float*)d_in[15];
    const float* mlp_w2  = (const float*)d_in[16];
    const float* mlp_b2  = (const float*)d_in[17];
    const float* treg_w  = (const float*)d_in[18];
    const float* treg_b  = (const float*)d_in[19];
    const float* sreg_w  = (const float*)d_in[20];
    const float* sreg_b  = (const float*)d_in[21];
    const float* daily   = (const float*)d_in[22];
    const float* weekly  = (const float*)d_in[23];
    const float* w_sp    = (const float*)d_in[24];
    float* out = (float*)d_out;

    char* ws = (char*)d_ws;
    __hip_bfloat16* h    = (__hip_bfloat16*)(ws);                 // BN*832 bf16 = 109,051,904
    float*          h0   = (float*)(ws + 109051904ULL);           // BN*64 f32   =  16,777,216
    float*          proj = (float*)(ws + 125829120ULL);           // N*64 f32    =     524,288
    float*          zet  = (float*)(ws + 126353408ULL);           // 64*99 f32 (pad 32,768)
    float*          edge = (float*)(ws + 126386176ULL);           // B*16*64 f32 =     131,072
    int*            cidx = (int*)  (ws + 126517248ULL);           // BN*8 i32    =   2,097,152
    unsigned int*   mask = (unsigned int*)(ws + 128614400ULL);    // BN u32      =     262,144
    __hip_bfloat16* spwb = (__hip_bfloat16*)(ws + 128876544ULL);  // 128*768 bf16=     196,608
    __hip_bfloat16* w1b  = (__hip_bfloat16*)(ws + 129073152ULL);  // 3*896*832   =   4,472,832
    __hip_bfloat16* w2b  = (__hip_bfloat16*)(ws + 133545984ULL);  // 3*896*832   =   4,472,832
    const size_t z1_off = 138018816ULL;
    __hip_bfloat16* z1   = (__hip_bfloat16*)(ws + z1_off);        // up to BN*832 bf16

    // adaptive z1 chunk (rows, multiple of 128)
    long long avail = (ws_size > z1_off) ? (long long)(ws_size - z1_off) : 0;
    long long chunk = (avail / (HT*2)) & ~127LL;
    if (chunk > BN) chunk = BN;
    if (chunk < 128) chunk = 128;

    // weight conversion with zero-padding to 128-multiple N (idempotent)
    f2b_pad_kernel<<<(128*HS + 255)/256, 256, 0, stream>>>(sp_w, spwb, 64, HS, 128);
    for (int i = 0; i < 3; ++i) {
        f2b_pad_kernel<<<(HTP*HT + 255)/256, 256, 0, stream>>>(
            mlp_w1 + (size_t)i*HT*HT, w1b + (size_t)i*HTP*HT, HT, HT, HTP);
        f2b_pad_kernel<<<(HTP*HT + 255)/256, 256, 0, stream>>>(
            mlp_w2 + (size_t)i*HT*HT, w2b + (size_t)i*HTP*HT, HT, HT, HTP);
    }

    et_z_kernel  <<<HCB, 64, 0, stream>>>(node_emb, et_w1, et_b1, zet);
    et_proj_kernel<<<NN, 64, 0, stream>>>(zet, et_w2, et_b2, proj);
    prep_kernel  <<<BN, 64, 0, stream>>>(hist, proj, tod_emb, dow_emb, ts_w, feat, kern,
                                         h, cidx, mask);
    // h0 = relu(enc_in @ sp_w^T + sp_b)  (K=768, NCOLS=64, C f32)
    gemm128<1,0,1,64><<<BN/128, 256, 0, stream>>>(
        (const unsigned short*)h, HT, (const unsigned short*)spwb, HS, sp_b, h0, DD, HS, 1);
    edge_kernel  <<<BB*NKER, 256, 0, stream>>>(h0, mask, feat, edge);
    msg_kernel   <<<BN/4, 256, 0, stream>>>(h0, edge, cidx, proj, h);
    // residual MLP stack, chunked over M by available workspace
    for (int i = 0; i < 3; ++i) {
        for (long long ms = 0; ms < BN; ms += chunk) {
            long long mm = (BN - ms < chunk) ? (BN - ms) : chunk;
            int grid = (int)(mm/128) * (HTP/128);
            gemm128<1,0,0,HT><<<grid, 256, 0, stream>>>(
                (const unsigned short*)(h + ms*HT), HT,
                (const unsigned short*)(w1b + (size_t)i*HTP*HT), HT,
                mlp_b1 + i*HT, z1, HT, HT, HTP/128);
            gemm128<0,1,0,HT><<<grid, 256, 0, stream>>>(
                (const unsigned short*)z1, HT,
                (const unsigned short*)(w2b + (size_t)i*HTP*HT), HT,
                mlp_b2 + i*HT, h + ms*HT, HT, HT, HTP/128);
        }
    }
    temporal_kernel<<<BN/256, 256, 0, stream>>>(hist, fut, daily, weekly, treg_w, treg_b, out);
    final_kernel <<<BN/4, 256, 0, stream>>>(h, sreg_w, sreg_b, w_sp, out);
}

// Round 9
// 1072.529 us; speedup vs baseline: 1.2428x; 1.2080x over previous
//
#include <hip/hip_runtime.h>
#include <hip/hip_bf16.h>
#include <math.h>

// ---------------- constants ----------------
#define BB 32
#define LL 12
#define NN 2048
#define DD 64
#define TOPK 8
#define NKER 16
#define OUTL 12
#define HS 768
#define HT 832
#define HTP 896     // HT padded to 128-multiple for 128-wide N tiles
#define HCB 99
#define BN (BB*NN)   // 65536 tokens

typedef __attribute__((ext_vector_type(8))) short bf16x8;
typedef __attribute__((ext_vector_type(4))) float f32x4;

// global -> LDS direct copy, 16B per lane (dest = wave-uniform base + lane*16)
#define GLOAD16(gp, lp) __builtin_amdgcn_global_load_lds( \
    (const __attribute__((address_space(1))) unsigned int*)(uintptr_t)(gp), \
    (__attribute__((address_space(3))) unsigned int*)(unsigned int)(uintptr_t)(lp), \
    16, 0, 0)

// ---------------- f32 -> bf16 convert with zero row padding ----------------
__global__ __launch_bounds__(256)
void f2b_pad_kernel(const float* __restrict__ x, __hip_bfloat16* __restrict__ y,
                    int rows, int cols, int prows) {
    int i = blockIdx.x * 256 + threadIdx.x;
    if (i >= prows * cols) return;
    int r = i / cols;
    y[i] = __float2bfloat16((r < rows) ? x[i] : 0.f);
}

// ---------------- EmbeddingTrainer ----------------
__global__ __launch_bounds__(64)
void et_z_kernel(const float* __restrict__ node_emb, const float* __restrict__ w1,
                 const float* __restrict__ b1, float* __restrict__ z) {
    int hh = blockIdx.x;     // 0..98
    int d  = threadIdx.x;    // 0..63
    float acc = 0.f;
    for (int nn = 0; nn < NN; ++nn)
        acc += node_emb[nn*DD + d] * w1[(size_t)hh*NN + nn];
    acc += b1[hh];
    z[d*HCB + hh] = fmaxf(acc, 0.f);
}

__global__ __launch_bounds__(64)
void et_proj_kernel(const float* __restrict__ z, const float* __restrict__ w2,
                    const float* __restrict__ b2, float* __restrict__ proj) {
    int nn = blockIdx.x;     // 0..2047
    int d  = threadIdx.x;
    float acc = 0.f;
    for (int hh = 0; hh < HCB; ++hh)
        acc += z[d*HCB + hh] * w2[nn*HCB + hh];
    proj[nn*DD + d] = acc + b2[nn];
}

// ---------------- per-token prep ----------------
__global__ __launch_bounds__(64)
void prep_kernel(const float* __restrict__ hist, const float* __restrict__ proj,
                 const float* __restrict__ tod_emb, const float* __restrict__ dow_emb,
                 const float* __restrict__ ts_w, const float* __restrict__ feat_emb,
                 const float* __restrict__ kern, __hip_bfloat16* __restrict__ h,
                 int* __restrict__ cidx, unsigned int* __restrict__ mask) {
    const int tok = blockIdx.x;
    const int b = tok >> 11, n = tok & (NN-1);
    const int lane = threadIdx.x;
    __shared__ float xs[LL];
    __shared__ float conn_s[NKER];
    __shared__ int   idx_s[TOPK];
    __shared__ float w_s[TOPK];

    if (lane < LL)
        xs[lane] = hist[((size_t)(b*LL + lane) * NN + n) * 3];
    __syncthreads();

    if (lane < NKER) {
        float xn = 0.f;
        #pragma unroll
        for (int l = 0; l < LL; ++l) xn += xs[l]*xs[l];
        xn = sqrtf(xn) + 1e-8f;
        float kn = 0.f;
        #pragma unroll
        for (int l = 0; l < LL; ++l) { float kv = kern[lane*LL + l]; kn += kv*kv; }
        kn = sqrtf(kn) + 1e-8f;
        float dot = 0.f;
        #pragma unroll
        for (int l = 0; l < LL; ++l) dot += (xs[l]/xn) * (kern[lane*LL + l]/kn);
        conn_s[lane] = dot;
    }
    __syncthreads();

    if (lane == 0) {
        float c[NKER];
        #pragma unroll
        for (int k = 0; k < NKER; ++k) c[k] = conn_s[k];
        unsigned int mk = 0;
        for (int j = 0; j < TOPK; ++j) {
            float best = -1e30f; int bi = 0;
            #pragma unroll
            for (int k = 0; k < NKER; ++k)
                if (c[k] > best) { best = c[k]; bi = k; }   // strict >: lowest index on ties
            idx_s[j] = bi;
            w_s[j] = 1.f / (1.f + expf(-best));
            c[bi] = -1e30f;
            mk |= (1u << bi);
            cidx[(size_t)tok*TOPK + j] = bi;
        }
        mask[tok] = mk;
    }
    __syncthreads();

    const int d = lane;
    float ts = 0.f;
    #pragma unroll
    for (int l = 0; l < LL; ++l) ts += xs[l] * ts_w[d*LL + l];
    size_t base = (size_t)tok * HT;
    h[base + d] = __float2bfloat16(ts);
    h[base + DD + d] = __float2bfloat16(proj[n*DD + d]);
    size_t last = ((size_t)(b*LL + (LL-1)) * NN + n) * 3;
    int ti = (int)(hist[last + 1] * 288.f);
    int wi = (int)(hist[last + 2] * 7.f);
    h[base + 2*DD + d] = __float2bfloat16(tod_emb[ti*DD + d]);
    h[base + 3*DD + d] = __float2bfloat16(dow_emb[wi*DD + d]);
    #pragma unroll
    for (int j = 0; j < TOPK; ++j)
        h[base + 4*DD + j*DD + d] = __float2bfloat16(w_s[j] * feat_emb[idx_s[j]*DD + d]);
}

// ---------------- bf16 MFMA GEMM (r4 structure, proven best) ----------------
// C[m][n] (+)= sum_k A[m][k]*W[n][k] + bias[n]
// 128x(NJ*32) tile, BK=64, 256 threads (2x2 waves, 4xNJ frags each).
// Plain 2-barrier loop; latency hidden by TLP: __launch_bounds__(256,4) caps
// total regs at 128 (64 acc + ~64 working) -> 4 blocks/CU (r4 had 3 at 144 regs).
// XOR-swizzled ds_read (slot' = slot ^ (row&7)); inverse-swizzled global source.
// W must have >= n0 + NJ*32 valid rows (zero-padded); epilogue guards col < NCOLS.
template<int RELU, int ACCUM, int CF32, int NCOLS, int NJ>
__global__ __launch_bounds__(256, 4)
void gemm128(const unsigned short* __restrict__ A, int lda,
             const unsigned short* __restrict__ W, int ldb,
             const float* __restrict__ bias,
             void* __restrict__ Cp, int ldc, int K, int ntiles) {
    __shared__ __align__(16) unsigned short As[128*64];   // 16 KB
    __shared__ __align__(16) unsigned short Bs[128*64];   // 16 KB (NJ=2 uses half)

    // bijective XCD swizzle
    int nwg = gridDim.x, bid = blockIdx.x;
    int q = nwg >> 3, r = nwg & 7;
    int xcd = bid & 7, idx = bid >> 3;
    int swz = ((xcd < r) ? xcd*(q+1) : r*(q+1) + (xcd-r)*q) + idx;
    const long long m0 = (long long)(swz / ntiles) * 128;
    const int n0 = (swz % ntiles) * (NJ*32);

    const int tid = threadIdx.x;
    const int wave = tid >> 6, lane = tid & 63;
    const int wr = wave >> 1, wc = wave & 1;
    const int l15 = lane & 15, l4 = lane >> 4;

    // staging coords: thread t fills LDS row qq*32 + (t>>3), slot t&7; global col
    // chunk (t&7) ^ ((t>>3)&7)  [inverse of the read swizzle; row&7 == (t>>3)&7]
    const int srow = tid >> 3;                       // 0..31
    const int gc = ((tid & 7) ^ ((tid >> 3) & 7)) * 8;
    const unsigned short* ag = A + (m0 + srow) * (long long)lda + gc;
    const unsigned short* bg = W + (long long)(n0 + srow) * ldb + gc;

    f32x4 acc[4][NJ] = {};

    for (int k0 = 0; k0 < K; k0 += 64) {
        #pragma unroll
        for (int qq = 0; qq < 4; ++qq)
            GLOAD16(ag + k0 + (long long)(qq*32)*lda, &As[(qq*256 + tid)*8]);
        #pragma unroll
        for (int qq = 0; qq < NJ; ++qq)
            GLOAD16(bg + k0 + (long long)(qq*32)*ldb, &Bs[(qq*256 + tid)*8]);
        __syncthreads();
        #pragma unroll
        for (int kh = 0; kh < 2; ++kh) {
            bf16x8 af[4], bf[NJ];
            #pragma unroll
            for (int i = 0; i < 4; ++i) {
                int ra = wr*64 + i*16 + l15;
                af[i] = *(const bf16x8*)&As[ra*64 + (((kh*4 + l4) ^ (ra & 7)) * 8)];
            }
            #pragma unroll
            for (int j = 0; j < NJ; ++j) {
                int rb = wc*(NJ*16) + j*16 + l15;
                bf[j] = *(const bf16x8*)&Bs[rb*64 + (((kh*4 + l4) ^ (rb & 7)) * 8)];
            }
            #pragma unroll
            for (int i = 0; i < 4; ++i)
                #pragma unroll
                for (int j = 0; j < NJ; ++j)
                    acc[i][j] = __builtin_amdgcn_mfma_f32_16x16x32_bf16(af[i], bf[j], acc[i][j], 0, 0, 0);
        }
        __syncthreads();
    }

    float* Cf = (float*)Cp;
    __hip_bfloat16* Cb = (__hip_bfloat16*)Cp;
    #pragma unroll
    for (int i = 0; i < 4; ++i) {
        #pragma unroll
        for (int j = 0; j < NJ; ++j) {
            int col = n0 + wc*(NJ*16) + j*16 + l15;
            if (col < NCOLS) {
                float bv = bias[col];
                #pragma unroll
                for (int rg = 0; rg < 4; ++rg) {
                    long long row = m0 + wr*64 + i*16 + l4*4 + rg;
                    float v = acc[i][j][rg] + bv;
                    if (RELU) v = fmaxf(v, 0.f);
                    if (CF32) {
                        Cf[row*ldc + col] = v;
                    } else {
                        if (ACCUM) v += __bfloat162float(Cb[row*ldc + col]);
                        Cb[row*ldc + col] = __float2bfloat16(v);
                    }
                }
            }
        }
    }
}

// ---------------- hyperedge aggregation (unconditional, pipelined) ----------------
__global__ __launch_bounds__(256)
void edge_kernel(const float* __restrict__ h0, const unsigned int* __restrict__ mask,
                 const float* __restrict__ feat_emb, float* __restrict__ edge) {
    int b = blockIdx.x >> 4, k = blockIdx.x & 15;
    int g = threadIdx.x >> 6, d = threadIdx.x & 63;
    __shared__ float accs[4][64];
    __shared__ int cnts[4];
    float acc = 0.f; int cnt = 0;
    size_t tb = (size_t)b * NN;
    #pragma unroll 4
    for (int nn = g; nn < NN; nn += 4) {
        unsigned int bit = (mask[tb + nn] >> k) & 1u;
        acc += (float)bit * h0[(tb + nn)*DD + d];
        cnt += (int)bit;
    }
    accs[g][d] = acc;
    if (d == 0) cnts[g] = cnt;
    __syncthreads();
    if (g == 0) {
        float a = accs[0][d] + accs[1][d] + accs[2][d] + accs[3][d];
        int c = cnts[0] + cnts[1] + cnts[2] + cnts[3];
        edge[((size_t)b*NKER + k)*DD + d] = a / fmaxf((float)c, 1.f) + feat_emb[k*DD + d];
    }
}

// msg + sp_out: h[tok][768+d] = h0 + msg/8 + proj
__global__ __launch_bounds__(256)
void msg_kernel(const float* __restrict__ h0, const float* __restrict__ edge,
                const int* __restrict__ cidx, const float* __restrict__ proj,
                __hip_bfloat16* __restrict__ h) {
    __shared__ float eS[NKER*DD];
    int t0 = blockIdx.x * 4;
    int b = t0 >> 11;
    for (int i = threadIdx.x; i < NKER*DD; i += 256) eS[i] = edge[(size_t)b*NKER*DD + i];
    __syncthreads();
    int g = threadIdx.x >> 6, lane = threadIdx.x & 63;
    int tok = t0 + g, n = tok & (NN-1);
    float m = 0.f;
    #pragma unroll
    for (int j = 0; j < TOPK; ++j)
        m += eS[cidx[(size_t)tok*TOPK + j]*DD + lane];
    float sp = h0[(size_t)tok*DD + lane] + m*0.125f + proj[n*DD + lane];
    h[(size_t)tok*HT + HS + lane] = __float2bfloat16(sp);
}

// ---------------- temporal branch -> forecast_t into d_out ----------------
__global__ __launch_bounds__(256)
void temporal_kernel(const float* __restrict__ hist, const float* __restrict__ fut,
                     const float* __restrict__ daily, const float* __restrict__ weekly,
                     const float* __restrict__ treg_w, const float* __restrict__ treg_b,
                     float* __restrict__ outp) {
    __shared__ int s_di[LL], s_wi[LL], s_df[OUTL], s_wf[OUTL];
    __shared__ float s_tw[OUTL*LL], s_tb[OUTL];
    int tid = threadIdx.x;
    int tok = blockIdx.x * 256 + tid;
    int b = tok >> 11, n = tok & (NN-1);
    if (tid < LL) {
        size_t hb = ((size_t)(b*LL + tid) * NN) * 3;
        s_di[tid] = (int)(hist[hb + 1] * 288.f);
        s_wi[tid] = (int)(hist[hb + 2] * 7.f);
        size_t fb = ((size_t)(b*OUTL + tid) * NN) * 3;
        s_df[tid] = (int)(fut[fb + 1] * 288.f);
        s_wf[tid] = (int)(fut[fb + 2] * 7.f);
        s_tb[tid] = treg_b[tid];
    }
    if (tid < OUTL*LL) s_tw[tid] = treg_w[tid];
    __syncthreads();
    float x[LL];
    float mean = 0.f;
    #pragma unroll
    for (int l = 0; l < LL; ++l) {
        x[l] = hist[((size_t)(b*LL + l) * NN + n) * 3];
        mean += x[l];
    }
    mean *= (1.f/12.f);
    float ss = 0.f;
    #pragma unroll
    for (int l = 0; l < LL; ++l) { float dd = x[l]-mean; ss += dd*dd; }
    float sd = sqrtf(ss*(1.f/11.f) + 1e-5f);
    float xr[LL];
    #pragma unroll
    for (int l = 0; l < LL; ++l)
        xr[l] = (x[l]-mean)/sd - daily[(size_t)s_di[l]*NN + n] - weekly[(size_t)s_wi[l]*NN + n];
    #pragma unroll
    for (int o = 0; o < OUTL; ++o) {
        float f = s_tb[o];
        #pragma unroll
        for (int l = 0; l < LL; ++l) f += xr[l]*s_tw[o*LL + l];
        f += daily[(size_t)s_df[o]*NN + n] + weekly[(size_t)s_wf[o]*NN + n];
        f = f*sd + mean;
        outp[((size_t)b*OUTL + o)*NN + n] = f;
    }
}

// ---------------- forecast_sp + blend ----------------
__global__ __launch_bounds__(256)
void final_kernel(const __hip_bfloat16* __restrict__ h, const float* __restrict__ sreg_w,
                  const float* __restrict__ sreg_b, const float* __restrict__ w_sp,
                  float* __restrict__ outp) {
    int g = threadIdx.x >> 6, lane = threadIdx.x & 63;
    int tok = blockIdx.x*4 + g;
    int b = tok >> 11, n = tok & (NN-1);
    float acc[OUTL];
    #pragma unroll
    for (int o = 0; o < OUTL; ++o) acc[o] = 0.f;
    size_t base = (size_t)tok * HT;
    for (int c = lane; c < HT; c += 64) {
        float hv = __bfloat162float(h[base + c]);
        #pragma unroll
        for (int o = 0; o < OUTL; ++o) acc[o] += hv * sreg_w[o*HT + c];
    }
    #pragma unroll
    for (int o = 0; o < OUTL; ++o) {
        #pragma unroll
        for (int s = 32; s >= 1; s >>= 1)
            acc[o] += __shfl_xor(acc[o], s, 64);
    }
    float v = 0.f;
    #pragma unroll
    for (int o = 0; o < OUTL; ++o) if (lane == o) v = acc[o] + sreg_b[o];
    if (lane < OUTL) {
        size_t oi = ((size_t)b*OUTL + lane)*NN + n;
        float t = outp[oi];
        float w = w_sp[n];
        outp[oi] = w*v + (1.f-w)*t;
    }
}

// ---------------- launch ----------------
extern "C" void kernel_launch(void* const* d_in, const int* in_sizes, int n_in,
                              void* d_out, int out_size, void* d_ws, size_t ws_size,
                              hipStream_t stream) {
    const float* hist    = (const float*)d_in[0];
    const float* fut     = (const float*)d_in[1];
    const float* node_emb= (const float*)d_in[2];
    const float* et_w1   = (const float*)d_in[3];
    const float* et_b1   = (const float*)d_in[4];
    const float* et_w2   = (const float*)d_in[5];
    const float* et_b2   = (const float*)d_in[6];
    const float* tod_emb = (const float*)d_in[7];
    const float* dow_emb = (const float*)d_in[8];
    const float* ts_w    = (const float*)d_in[9];
    const float* feat    = (const float*)d_in[10];
    const float* kern    = (const float*)d_in[11];
    const float* sp_w    = (const float*)d_in[12];
    const float* sp_b    = (const float*)d_in[13];
    const float* mlp_w1  = (const float*)d_in[14];
    const float* mlp_b1  = (const float*)d_in[15];
    const float* mlp_w2  = (const float*)d_in[16];
    const float* mlp_b2  = (const float*)d_in[17];
    const float* treg_w  = (const float*)d_in[18];
    const float* treg_b  = (const float*)d_in[19];
    const float* sreg_w  = (const float*)d_in[20];
    const float* sreg_b  = (const float*)d_in[21];
    const float* daily   = (const float*)d_in[22];
    const float* weekly  = (const float*)d_in[23];
    const float* w_sp    = (const float*)d_in[24];
    float* out = (float*)d_out;

    char* ws = (char*)d_ws;
    __hip_bfloat16* h    = (__hip_bfloat16*)(ws);                 // BN*832 bf16 = 109,051,904
    float*          h0   = (float*)(ws + 109051904ULL);           // BN*64 f32   =  16,777,216
    float*          proj = (float*)(ws + 125829120ULL);           // N*64 f32    =     524,288
    float*          zet  = (float*)(ws + 126353408ULL);           // 64*99 f32 (pad 32,768)
    float*          edge = (float*)(ws + 126386176ULL);           // B*16*64 f32 =     131,072
    int*            cidx = (int*)  (ws + 126517248ULL);           // BN*8 i32    =   2,097,152
    unsigned int*   mask = (unsigned int*)(ws + 128614400ULL);    // BN u32      =     262,144
    __hip_bfloat16* spwb = (__hip_bfloat16*)(ws + 128876544ULL);  // 128*768 bf16=     196,608
    __hip_bfloat16* w1b  = (__hip_bfloat16*)(ws + 129073152ULL);  // 3*896*832   =   4,472,832
    __hip_bfloat16* w2b  = (__hip_bfloat16*)(ws + 133545984ULL);  // 3*896*832   =   4,472,832
    const size_t z1_off = 138018816ULL;
    __hip_bfloat16* z1   = (__hip_bfloat16*)(ws + z1_off);        // up to BN*832 bf16

    // adaptive z1 chunk (rows, multiple of 128)
    long long avail = (ws_size > z1_off) ? (long long)(ws_size - z1_off) : 0;
    long long chunk = (avail / (HT*2)) & ~127LL;
    if (chunk > BN) chunk = BN;
    if (chunk < 128) chunk = 128;

    // weight conversion with zero-padding to 128-multiple N (idempotent)
    f2b_pad_kernel<<<(128*HS + 255)/256, 256, 0, stream>>>(sp_w, spwb, 64, HS, 128);
    for (int i = 0; i < 3; ++i) {
        f2b_pad_kernel<<<(HTP*HT + 255)/256, 256, 0, stream>>>(
            mlp_w1 + (size_t)i*HT*HT, w1b + (size_t)i*HTP*HT, HT, HT, HTP);
        f2b_pad_kernel<<<(HTP*HT + 255)/256, 256, 0, stream>>>(
            mlp_w2 + (size_t)i*HT*HT, w2b + (size_t)i*HTP*HT, HT, HT, HTP);
    }

    et_z_kernel  <<<HCB, 64, 0, stream>>>(node_emb, et_w1, et_b1, zet);
    et_proj_kernel<<<NN, 64, 0, stream>>>(zet, et_w2, et_b2, proj);
    prep_kernel  <<<BN, 64, 0, stream>>>(hist, proj, tod_emb, dow_emb, ts_w, feat, kern,
                                         h, cidx, mask);
    // h0 = relu(enc_in @ sp_w^T + sp_b)  (K=768, NCOLS=64, NJ=2: 64-wide tile, C f32)
    gemm128<1,0,1,64,2><<<BN/128, 256, 0, stream>>>(
        (const unsigned short*)h, HT, (const unsigned short*)spwb, HS, sp_b, h0, DD, HS, 1);
    edge_kernel  <<<BB*NKER, 256, 0, stream>>>(h0, mask, feat, edge);
    msg_kernel   <<<BN/4, 256, 0, stream>>>(h0, edge, cidx, proj, h);
    // residual MLP stack, chunked over M by available workspace
    for (int i = 0; i < 3; ++i) {
        for (long long ms = 0; ms < BN; ms += chunk) {
            long long mm = (BN - ms < chunk) ? (BN - ms) : chunk;
            int grid = (int)(mm/128) * (HTP/128);
            gemm128<1,0,0,HT,4><<<grid, 256, 0, stream>>>(
                (const unsigned short*)(h + ms*HT), HT,
                (const unsigned short*)(w1b + (size_t)i*HTP*HT), HT,
                mlp_b1 + i*HT, z1, HT, HT, HTP/128);
            gemm128<0,1,0,HT,4><<<grid, 256, 0, stream>>>(
                (const unsigned short*)z1, HT,
                (const unsigned short*)(w2b + (size_t)i*HTP*HT), HT,
                mlp_b2 + i*HT, h + ms*HT, HT, HT, HTP/128);
        }
    }
    temporal_kernel<<<BN/256, 256, 0, stream>>>(hist, fut, daily, weekly, treg_w, treg_b, out);
    final_kernel <<<BN/4, 256, 0, stream>>>(h, sreg_w, sreg_b, w_sp, out);
}